// Round 2
// baseline (127.585 us; speedup 1.0000x reference)
//
#include <hip/hip_runtime.h>

#define BB 4
#define CCH 64
#define HH 256
#define WW 256
#define PP (HH*WW)     // 65536
#define NS 256         // nh*nw = 16*16
#define NW 16

// rel[k] = (k/3 - 1)*16 + (k%3 - 1)  -> {-17,-16,-15,-1,0,1,15,16,17}

// ---------------- Kernel A: superpixel means -> spix[b][s][c] ----------------
__global__ __launch_bounds__(256) void kA_spix_init(const float* __restrict__ x,
                                                    float* __restrict__ spix) {
    int blk = blockIdx.x;          // 4*64*16
    int i = blk & 15;              // superpixel row
    int c = (blk >> 4) & 63;
    int b = blk >> 10;
    int t = threadIdx.x;           // column 0..255
    const float* base = x + ((size_t)(b*CCH + c))*PP + (size_t)i*16*WW + t;
    float s = 0.f;
    #pragma unroll
    for (int r = 0; r < 16; ++r) s += base[(size_t)r*WW];
    #pragma unroll
    for (int off = 8; off; off >>= 1) s += __shfl_down(s, off, 16);
    if ((t & 15) == 0) {
        int j = t >> 4;
        spix[((size_t)b*NS + (i*16 + j))*CCH + c] = s * (1.f/256.f);
    }
}

// ---------------- Kernel F: fused aff (iter 0) + per-block partials ----------
// One block per (b, superpixel l). All 256 pixels share label l.
// partial[b][k][l][c] = sum_{p in block l} aff[k][p] * x[c][p]
// wpart[b][k][l]      = sum_{p in block l} aff[k][p]
__global__ __launch_bounds__(256) void kF_fused(const float* __restrict__ x,
                                                const float* __restrict__ spix,
                                                float* __restrict__ partial,
                                                float* __restrict__ wpart) {
    __shared__ float sp[9][64];
    __shared__ float sn[9];
    __shared__ float affL[9][260];
    __shared__ float pixT[32][257];   // 32.9 KB; also aliased as red[8][9][33]
    float (*red)[9][33] = (float(*)[9][33])&pixT[0][0];

    int blk = blockIdx.x;             // B*NS = 1024
    int l = blk & 255, b = blk >> 8;
    int by = l >> 4, bx = l & 15;
    int t = threadIdx.x;

    // load 9 neighbor spix vectors (flat-index wrap semantics: valid iff 0<=l+rel<NS)
    for (int idx = t; idx < 9*64; idx += 256) {
        int k = idx >> 6, c = idx & 63;
        int rel = (k/3 - 1)*16 + (k % 3) - 1;
        int s = l + rel;
        float v = 0.f;
        if (s >= 0 && s < NS) v = spix[((size_t)b*NS + s)*CCH + c];
        sp[k][c] = v;
    }
    __syncthreads();
    if (t < 9) {
        float s = 0.f;
        #pragma unroll 8
        for (int c = 0; c < CCH; ++c) { float v = sp[t][c]; s += v*v; }
        sn[t] = s;
    }
    __syncthreads();

    int ty = t >> 4, tx = t & 15;
    int gp = (by*16 + ty)*WW + bx*16 + tx;
    const float* px = x + (size_t)b*CCH*PP + gp;

    float cross[9];
    #pragma unroll
    for (int k = 0; k < 9; ++k) cross[k] = 0.f;
    float pn = 0.f;
    for (int c = 0; c < CCH; ++c) {
        float v = px[(size_t)c*PP];
        pn += v*v;
        #pragma unroll
        for (int k = 0; k < 9; ++k) cross[k] += sp[k][c] * v;
    }

    float e[9];
    float m = -1e30f;
    #pragma unroll
    for (int k = 0; k < 9; ++k) {
        int rel = (k/3 - 1)*16 + (k % 3) - 1;
        int s = l + rel;
        bool valid = (s >= 0) && (s < NS);
        float z = -(pn - 2.f*cross[k] + sn[k]);
        e[k] = valid ? z : -3.0e38f;
        if (valid && z > m) m = z;
    }
    float sum = 0.f;
    #pragma unroll
    for (int k = 0; k < 9; ++k) {
        float v = (e[k] > -2.9e38f) ? expf(e[k] - m) : 0.f;
        e[k] = v;
        sum += v;
    }
    float inv = 1.f / sum;
    #pragma unroll
    for (int k = 0; k < 9; ++k) affL[k][t] = e[k] * inv;
    __syncthreads();

    // ---- partial accumulation (kC body, x re-read is cache-hot) ----
    int cl = t & 31, q = t >> 5;
    for (int half = 0; half < 2; ++half) {
        #pragma unroll 4
        for (int ci = 0; ci < 32; ++ci)
            pixT[ci][t] = x[((size_t)(b*CCH + half*32 + ci))*PP + gp];
        __syncthreads();
        float acc[9];
        #pragma unroll
        for (int k = 0; k < 9; ++k) acc[k] = 0.f;
        for (int i = 0; i < 32; ++i) {
            int lp = q*32 + i;
            float v = pixT[cl][lp];
            #pragma unroll
            for (int k = 0; k < 9; ++k) acc[k] += affL[k][lp] * v;
        }
        __syncthreads();                   // acc done everywhere before red aliases pixT
        #pragma unroll
        for (int k = 0; k < 9; ++k) red[q][k][cl] = acc[k];
        __syncthreads();
        for (int tt = t; tt < 9*32; tt += 256) {
            int k = tt >> 5, c2 = tt & 31;
            float s = 0.f;
            #pragma unroll
            for (int qq = 0; qq < 8; ++qq) s += red[qq][k][c2];
            partial[(((size_t)b*9 + k)*NS + l)*CCH + half*32 + c2] = s;
        }
        __syncthreads();
    }
    // wpart
    if (t < 72) {
        int k = t >> 3, seg = t & 7;
        float s = 0.f;
        #pragma unroll
        for (int i = 0; i < 32; ++i) s += affL[k][seg*32 + i];
        red[seg][k][32] = s;
    }
    __syncthreads();
    if (t < 9) {
        float s = 0.f;
        #pragma unroll
        for (int qq = 0; qq < 8; ++qq) s += red[qq][t][32];
        wpart[((size_t)b*9 + t)*NS + l] = s;
    }
}

// ---------------- Kernel B: per-pixel 9-neighbor softmax -> aff9[b][k][p] ----
__global__ __launch_bounds__(256) void kB_aff(const float* __restrict__ x,
                                              const float* __restrict__ spix,
                                              float* __restrict__ aff9) {
    __shared__ float spw[50][65];   // flat label window [base..base+49], padded
    __shared__ float snw[50];
    int blk = blockIdx.x;           // B*H = 1024
    int y = blk & 255;
    int b = blk >> 8;
    int t = threadIdx.x;            // x coordinate
    int ly = y >> 4;
    int base = ly*16 - 17;

    for (int idx = t; idx < 50*CCH; idx += 256) {
        int j = idx >> 6, c = idx & 63;
        int g = base + j;
        float v = 0.f;
        if (g >= 0 && g < NS) v = spix[((size_t)b*NS + g)*CCH + c];
        spw[j][c] = v;
    }
    __syncthreads();
    if (t < 50) {
        float s = 0.f;
        #pragma unroll 8
        for (int c = 0; c < CCH; ++c) { float v = spw[t][c]; s += v*v; }
        snw[t] = s;
    }
    __syncthreads();

    int p = y*WW + t;
    const float* px = x + (size_t)b*CCH*PP + p;
    int wl = 17 + (t >> 4);         // own label's window index
    int nk[9];
    #pragma unroll
    for (int k = 0; k < 9; ++k) nk[k] = wl + (k/3 - 1)*16 + (k%3 - 1);

    float cross[9];
    #pragma unroll
    for (int k = 0; k < 9; ++k) cross[k] = 0.f;
    float pn = 0.f;
    for (int c = 0; c < CCH; ++c) {
        float v = px[(size_t)c*PP];
        pn += v*v;
        #pragma unroll
        for (int k = 0; k < 9; ++k) cross[k] += spw[nk[k]][c] * v;
    }

    int label = ly*16 + (t >> 4);
    float e[9];
    float m = -1e30f;
    #pragma unroll
    for (int k = 0; k < 9; ++k) {
        int rel = (k/3 - 1)*16 + (k%3 - 1);
        int sidx = label + rel;
        bool valid = (sidx >= 0) && (sidx < NS);
        float z = -(pn - 2.f*cross[k] + snw[nk[k]]);
        e[k] = valid ? z : -3.0e38f;
        if (valid && z > m) m = z;
    }
    float sum = 0.f;
    #pragma unroll
    for (int k = 0; k < 9; ++k) {
        float v = (e[k] > -2.9e38f) ? expf(e[k] - m) : 0.f;
        e[k] = v;
        sum += v;
    }
    float inv = 1.f / sum;
    #pragma unroll
    for (int k = 0; k < 9; ++k)
        aff9[((size_t)b*9 + k)*PP + p] = e[k] * inv;
}

// ---------------- Kernel D: gather + divide -> new spix ---------------------
__global__ __launch_bounds__(256) void kD_update(const float* __restrict__ partial,
                                                 const float* __restrict__ wpart,
                                                 float* __restrict__ spix) {
    int gid = blockIdx.x*256 + threadIdx.x;   // 4*256*64 = 65536
    int c = gid & 63, s = (gid >> 6) & 255, b = gid >> 14;
    float num = 0.f, den = 0.f;
    #pragma unroll
    for (int k = 0; k < 9; ++k) {
        int rel = (k/3 - 1)*16 + (k%3 - 1);
        int l = s - rel;
        if (l >= 0 && l < NS) {
            num += partial[(((size_t)b*9 + k)*NS + l)*CCH + c];
            den += wpart[((size_t)b*9 + k)*NS + l];
        }
    }
    spix[((size_t)b*NS + s)*CCH + c] = num / (den + 1e-16f);
}

// ---------------- Kernel E: dense output write ------------------------------
__global__ __launch_bounds__(256) void kE_out(const float* __restrict__ aff9,
                                              float* __restrict__ out,
                                              int out_size) {
    int gid = blockIdx.x*256 + threadIdx.x;   // 16,777,216 float4s
    int row = gid >> 14;                      // b*NS + s
    int col4 = gid & 16383;
    int s = row & 255, b = row >> 8;
    int p = col4 << 2;
    int l = ((p >> 12) << 4) | ((p & 255) >> 4);   // (py>>4)*16 + (px>>4)
    int diff = s - l + 17;
    float4 v = make_float4(0.f, 0.f, 0.f, 0.f);
    if ((unsigned)diff <= 34u && (diff & 15) < 3) {
        int k = (diff >> 4)*3 + (diff & 15);
        const float4* src = (const float4*)(aff9 + ((size_t)b*9 + k)*PP);
        v = src[col4];
    }
    ((float4*)out)[gid] = v;
    if (gid == 0) out[out_size - 1] = 256.0f;   // Output 1: ns
}

extern "C" void kernel_launch(void* const* d_in, const int* in_sizes, int n_in,
                              void* d_out, int out_size, void* d_ws, size_t ws_size,
                              hipStream_t stream) {
    (void)in_sizes; (void)n_in; (void)ws_size;
    const float* x = (const float*)d_in[0];
    float* out = (float*)d_out;
    float* ws = (float*)d_ws;

    float* spix    = ws;                         // 65,536 floats
    float* aff9    = spix + (size_t)BB*NS*CCH;   // 2,359,296 floats
    float* partial = aff9 + (size_t)BB*9*PP;     // 589,824 floats
    float* wpart   = partial + (size_t)BB*9*NS*CCH; // 9,216 floats

    kA_spix_init<<<BB*CCH*16, 256, 0, stream>>>(x, spix);
    kF_fused<<<BB*NS, 256, 0, stream>>>(x, spix, partial, wpart);
    kD_update<<<BB*NS*CCH/256, 256, 0, stream>>>(partial, wpart, spix);
    kB_aff<<<BB*HH, 256, 0, stream>>>(x, spix, aff9);
    kE_out<<<(BB*NS*PP/4)/256, 256, 0, stream>>>(aff9, out, out_size);
}

// Round 3
// 114.526 us; speedup vs baseline: 1.1140x; 1.1140x over previous
//
#include <hip/hip_runtime.h>

#define BB 4
#define CCH 64
#define HH 256
#define WW 256
#define PP (HH*WW)     // 65536
#define NS 256         // nh*nw = 16*16

// rel[k] = (k/3 - 1)*16 + (k%3 - 1)  -> {-17,-16,-15,-1,0,1,15,16,17}

// ---------------- Kernel A: superpixel means -> spix[b][s][c] ----------------
__global__ __launch_bounds__(256) void kA_spix_init(const float* __restrict__ x,
                                                    float* __restrict__ spix) {
    int blk = blockIdx.x;          // 4*64*16
    int i = blk & 15;              // superpixel row
    int c = (blk >> 4) & 63;
    int b = blk >> 10;
    int t = threadIdx.x;           // column 0..255
    const float* base = x + ((size_t)(b*CCH + c))*PP + (size_t)i*16*WW + t;
    float s = 0.f;
    #pragma unroll
    for (int r = 0; r < 16; ++r) s += base[(size_t)r*WW];
    #pragma unroll
    for (int off = 8; off; off >>= 1) s += __shfl_down(s, off, 16);
    if ((t & 15) == 0) {
        int j = t >> 4;
        spix[((size_t)b*NS + (i*16 + j))*CCH + c] = s * (1.f/256.f);
    }
}

// ---------------- Kernel F: fused aff (iter 0) + per-block partials ----------
// Single x pass: 64 channels held in registers, spilled to LDS for transpose.
__global__ __launch_bounds__(256) void kF_fused(const float* __restrict__ x,
                                                const float* __restrict__ spix,
                                                float* __restrict__ partial,
                                                float* __restrict__ wpart) {
    __shared__ float sp[9][64];
    __shared__ float sn[9];
    __shared__ float affL[9][260];
    __shared__ float pixT[32][257];
    __shared__ float red[4][9][33];
    __shared__ float wsum[4][9];

    int blk = blockIdx.x;             // B*NS = 1024
    int l = blk & 255, b = blk >> 8;
    int by = l >> 4, bx = l & 15;
    int t = threadIdx.x;
    int lane = t & 63, w = t >> 6;

    // 9 neighbor spix vectors (flat-index wrap semantics: valid iff 0<=l+rel<NS)
    for (int idx = t; idx < 9*64; idx += 256) {
        int k = idx >> 6, c = idx & 63;
        int rel = (k/3 - 1)*16 + (k % 3) - 1;
        int s = l + rel;
        float v = 0.f;
        if (s >= 0 && s < NS) v = spix[((size_t)b*NS + s)*CCH + c];
        sp[k][c] = v;
    }
    __syncthreads();
    if (t < 9) {
        float s = 0.f;
        #pragma unroll 8
        for (int c = 0; c < CCH; ++c) { float v = sp[t][c]; s += v*v; }
        sn[t] = s;
    }
    __syncthreads();

    int ty = t >> 4, tx = t & 15;
    int gp = (by*16 + ty)*WW + bx*16 + tx;
    const float* px = x + (size_t)b*CCH*PP + gp;

    float xr[64];
    float cross[9];
    #pragma unroll
    for (int k = 0; k < 9; ++k) cross[k] = 0.f;
    float pn = 0.f;
    #pragma unroll
    for (int c = 0; c < CCH; ++c) {
        float v = px[(size_t)c*PP];
        xr[c] = v;
        pn += v*v;
        #pragma unroll
        for (int k = 0; k < 9; ++k) cross[k] += sp[k][c] * v;
    }

    float e[9];
    float m = -1e30f;
    #pragma unroll
    for (int k = 0; k < 9; ++k) {
        int rel = (k/3 - 1)*16 + (k % 3) - 1;
        int s = l + rel;
        bool valid = (s >= 0) && (s < NS);
        float z = -(pn - 2.f*cross[k] + sn[k]);
        e[k] = valid ? z : -3.0e38f;
        if (valid && z > m) m = z;
    }
    float sum = 0.f;
    #pragma unroll
    for (int k = 0; k < 9; ++k) {
        float v = (e[k] > -2.9e38f) ? expf(e[k] - m) : 0.f;
        e[k] = v;
        sum += v;
    }
    float inv = 1.f / sum;
    #pragma unroll
    for (int k = 0; k < 9; ++k) { e[k] *= inv; affL[k][t] = e[k]; }

    // wpart: butterfly reduce aff over the wave, then across waves
    #pragma unroll
    for (int k = 0; k < 9; ++k) {
        float v = e[k];
        #pragma unroll
        for (int off = 32; off; off >>= 1) v += __shfl_xor(v, off);
        if (lane == 0) wsum[w][k] = v;
    }
    __syncthreads();
    if (t < 9) {
        wpart[((size_t)b*9 + t)*NS + l] =
            wsum[0][t] + wsum[1][t] + wsum[2][t] + wsum[3][t];
    }

    // partial accumulation from register-held x values
    int cl = t & 31, q = t >> 5;
    #pragma unroll
    for (int half = 0; half < 2; ++half) {
        if (half) __syncthreads();        // red/pixT rewrite hazard
        #pragma unroll
        for (int ci = 0; ci < 32; ++ci) pixT[ci][t] = xr[half*32 + ci];
        __syncthreads();
        float acc[9];
        #pragma unroll
        for (int k = 0; k < 9; ++k) acc[k] = 0.f;
        for (int i = 0; i < 32; ++i) {
            int lp = q*32 + i;
            float v = pixT[cl][lp];
            #pragma unroll
            for (int k = 0; k < 9; ++k) acc[k] += affL[k][lp] * v;
        }
        #pragma unroll
        for (int k = 0; k < 9; ++k) acc[k] += __shfl_down(acc[k], 32);
        if (lane < 32) {
            #pragma unroll
            for (int k = 0; k < 9; ++k) red[w][k][cl] = acc[k];
        }
        __syncthreads();
        for (int tt = t; tt < 9*32; tt += 256) {
            int k = tt >> 5, c2 = tt & 31;
            float s = red[0][k][c2] + red[1][k][c2] + red[2][k][c2] + red[3][k][c2];
            partial[(((size_t)b*9 + k)*NS + l)*CCH + half*32 + c2] = s;
        }
    }
}

// ---------------- Kernel D: gather + divide -> new spix ---------------------
__global__ __launch_bounds__(256) void kD_update(const float* __restrict__ partial,
                                                 const float* __restrict__ wpart,
                                                 float* __restrict__ spix) {
    int gid = blockIdx.x*256 + threadIdx.x;   // 65536
    int c = gid & 63, s = (gid >> 6) & 255, b = gid >> 14;
    float num = 0.f, den = 0.f;
    #pragma unroll
    for (int k = 0; k < 9; ++k) {
        int rel = (k/3 - 1)*16 + (k%3 - 1);
        int l = s - rel;
        if (l >= 0 && l < NS) {
            num += partial[(((size_t)b*9 + k)*NS + l)*CCH + c];
            den += wpart[((size_t)b*9 + k)*NS + l];
        }
    }
    spix[((size_t)b*NS + s)*CCH + c] = num / (den + 1e-16f);
}

// ---------------- Kernel BE: fused final aff + dense output write -----------
// One block per (b, pixel-row y). Computes the 9-way softmax for its 256
// pixels into LDS, then writes all 256 dense output row-segments directly.
__global__ __launch_bounds__(256) void kBE(const float* __restrict__ x,
                                           const float* __restrict__ spix,
                                           float* __restrict__ out,
                                           int out_size) {
    __shared__ float spw[50][65];   // flat label window [base..base+49]
    __shared__ float snw[50];
    __shared__ float affL[9][260];  // row stride 1040 B (16B-aligned)
    int blk = blockIdx.x;           // B*H = 1024
    int y = blk & 255;
    int b = blk >> 8;
    int t = threadIdx.x;            // x coordinate
    int ly = y >> 4;
    int base = ly*16 - 17;

    for (int idx = t; idx < 50*CCH; idx += 256) {
        int j = idx >> 6, c = idx & 63;
        int g = base + j;
        float v = 0.f;
        if (g >= 0 && g < NS) v = spix[((size_t)b*NS + g)*CCH + c];
        spw[j][c] = v;
    }
    __syncthreads();
    if (t < 50) {
        float s = 0.f;
        #pragma unroll 8
        for (int c = 0; c < CCH; ++c) { float v = spw[t][c]; s += v*v; }
        snw[t] = s;
    }
    __syncthreads();

    int p = y*WW + t;
    const float* px = x + (size_t)b*CCH*PP + p;
    int wl = 17 + (t >> 4);
    int nk[9];
    #pragma unroll
    for (int k = 0; k < 9; ++k) nk[k] = wl + (k/3 - 1)*16 + (k%3 - 1);

    float cross[9];
    #pragma unroll
    for (int k = 0; k < 9; ++k) cross[k] = 0.f;
    float pn = 0.f;
    for (int c = 0; c < CCH; ++c) {
        float v = px[(size_t)c*PP];
        pn += v*v;
        #pragma unroll
        for (int k = 0; k < 9; ++k) cross[k] += spw[nk[k]][c] * v;
    }

    int label = ly*16 + (t >> 4);
    float e[9];
    float m = -1e30f;
    #pragma unroll
    for (int k = 0; k < 9; ++k) {
        int rel = (k/3 - 1)*16 + (k%3 - 1);
        int sidx = label + rel;
        bool valid = (sidx >= 0) && (sidx < NS);
        float z = -(pn - 2.f*cross[k] + snw[nk[k]]);
        e[k] = valid ? z : -3.0e38f;
        if (valid && z > m) m = z;
    }
    float sum = 0.f;
    #pragma unroll
    for (int k = 0; k < 9; ++k) {
        float v = (e[k] > -2.9e38f) ? expf(e[k] - m) : 0.f;
        e[k] = v;
        sum += v;
    }
    float inv = 1.f / sum;
    #pragma unroll
    for (int k = 0; k < 9; ++k) affL[k][t] = e[k] * inv;
    __syncthreads();

    // ---- dense write: wave w writes rows s ≡ w (mod 4), 1 KB per store row
    int w = t >> 6, lane = t & 63;
    int px4 = lane * 4;
    int labelbase = ly*16 + (px4 >> 4);
    float* orow = out + (size_t)b*NS*PP + (size_t)y*WW + px4;
    #pragma unroll 8
    for (int r = 0; r < 64; ++r) {
        int s = w + 4*r;
        int diff = s - labelbase + 17;
        float4 v = make_float4(0.f, 0.f, 0.f, 0.f);
        if ((unsigned)diff <= 34u && (diff & 15) < 3) {
            int k = (diff >> 4)*3 + (diff & 15);
            v = *(const float4*)&affL[k][px4];
        }
        *(float4*)(orow + (size_t)s*PP) = v;
    }
    if (blk == 0 && t == 0) out[out_size - 1] = 256.0f;   // Output 1: ns
}

extern "C" void kernel_launch(void* const* d_in, const int* in_sizes, int n_in,
                              void* d_out, int out_size, void* d_ws, size_t ws_size,
                              hipStream_t stream) {
    (void)in_sizes; (void)n_in; (void)ws_size;
    const float* x = (const float*)d_in[0];
    float* out = (float*)d_out;
    float* ws = (float*)d_ws;

    float* spix    = ws;                            // 65,536 floats
    float* partial = spix + (size_t)BB*NS*CCH;      // 589,824 floats
    float* wpart   = partial + (size_t)BB*9*NS*CCH; // 9,216 floats

    kA_spix_init<<<BB*CCH*16, 256, 0, stream>>>(x, spix);
    kF_fused<<<BB*NS, 256, 0, stream>>>(x, spix, partial, wpart);
    kD_update<<<BB*NS*CCH/256, 256, 0, stream>>>(partial, wpart, spix);
    kBE<<<BB*HH, 256, 0, stream>>>(x, spix, out, out_size);
}